// Round 7
// baseline (329.764 us; speedup 1.0000x reference)
//
#include <hip/hip_runtime.h>

// ---- static problem config (mirrors reference init) ----
#define BB   4
#define NNC  4          // cameras
#define DDEP 41
#define FHH  16
#define FWW  44
#define CC   64
#define NXX  240
#define NYY  240
#define NVOX (BB*NYY*NXX)            // 230400 BEV cells (vz==0 plane)
#define NTRI (BB*NNC*DDEP*FWW)       // 28864 (b,n,d,u) column triples
#define CELLS 128                    // cells per assemble block
#define NBLK (NVOX/CELLS)            // 1800 blocks (57600 % 128 == 0, no b-cross)

// ---- workspace layout (bytes) ----
#define W_REC 0                      // u64 rec[NTRI] = (mask<<32)|vb ; 231 KB
// no other workspace; nothing is memset.

typedef float f4 __attribute__((ext_vector_type(4)));

// Replicate LAPACK sgetrf+strti2 on an UPPER-TRIANGULAR 3x3 in fp32, op-for-op.
__device__ __forceinline__ void inv3x3_upper_f32(const float K[9], float o[9]) {
    float a00 = __fdiv_rn(1.0f, K[0]);
    float a11 = __fdiv_rn(1.0f, K[4]);
    float a22 = __fdiv_rn(1.0f, K[8]);
    float b01 = __fmul_rn(-a11, __fmul_rn(a00, K[1]));
    float x0 = __fadd_rn(__fmul_rn(a00, K[2]), __fmul_rn(b01, K[5]));
    float x1 = __fmul_rn(a11, K[5]);
    float b02 = __fmul_rn(-a22, x0);
    float b12 = __fmul_rn(-a22, x1);
    o[0]=a00; o[1]=b01; o[2]=b02;
    o[3]=0.0f; o[4]=a11; o[5]=b12;
    o[6]=0.0f; o[7]=0.0f; o[8]=a22;
}

// v8 geom_rec: geometry chain UNCHANGED (bit-exact). Output is now a DENSE
// per-triple record — one plain 8 B store by the h==0 lane. ZERO atomics,
// and the array is fully overwritten every launch (no memset needed).
// This is the decisive experiment for geom's unexplained 87 us: same math,
// same loads, same grid — only the atomic-RMW+dependent-store tail removed.
__global__ void __launch_bounds__(256) geom_rec(
        const float* __restrict__ rots,
        const float* __restrict__ trans,
        const float* __restrict__ intrins,
        const float* __restrict__ post_rots,
        const float* __restrict__ post_trans,
        unsigned long long* __restrict__ rec) {
    int tid  = threadIdx.x;
    int wid  = tid >> 6;
    int lane = tid & 63;
    int sub  = lane >> 4;
    int h    = lane & 15;
    int tri  = (blockIdx.x*4 + wid)*4 + sub;     // NTRI = 16*1804 exactly

    int w    = tri % FWW;
    int rest = tri / FWW;
    int d    = rest % DDEP;
    int bn   = rest / DDEP;

    float K[9], PR[9], R[9];
    #pragma unroll
    for (int i = 0; i < 9; ++i) {
        K[i]  = intrins[bn*9 + i];
        PR[i] = post_rots[bn*9 + i];
        R[i]  = rots[bn*9 + i];
    }
    float Ki[9], PRi[9];
    inv3x3_upper_f32(K, Ki);
    inv3x3_upper_f32(PR, PRi);
    float C[9];
    #pragma unroll
    for (int i = 0; i < 3; ++i)
        #pragma unroll
        for (int j = 0; j < 3; ++j) {
            float s = __fmul_rn(R[i*3+0], Ki[0*3+j]);
            s = __fadd_rn(s, __fmul_rn(R[i*3+1], Ki[1*3+j]));
            s = __fadd_rn(s, __fmul_rn(R[i*3+2], Ki[2*3+j]));
            C[i*3+j] = s;
        }
    float ptx = post_trans[bn*3+0], pty = post_trans[bn*3+1], ptz = post_trans[bn*3+2];
    float trx = trans[bn*3+0], try_ = trans[bn*3+1], trz = trans[bn*3+2];

    float u  = (float)((double)w * (703.0/43.0));   // np.linspace: f64 then f32 cast
    float v  = (float)((double)h * 17.0);
    float dd = (float)(4 + d);

    float p0x = __fsub_rn(u,  ptx);
    float p0y = __fsub_rn(v,  pty);
    float p0z = __fsub_rn(dd, ptz);
    float p1x = __fadd_rn(__fadd_rn(__fmul_rn(PRi[0],p0x), __fmul_rn(PRi[1],p0y)), __fmul_rn(PRi[2],p0z));
    float p1y = __fadd_rn(__fadd_rn(__fmul_rn(PRi[3],p0x), __fmul_rn(PRi[4],p0y)), __fmul_rn(PRi[5],p0z));
    float p1z = __fadd_rn(__fadd_rn(__fmul_rn(PRi[6],p0x), __fmul_rn(PRi[7],p0y)), __fmul_rn(PRi[8],p0z));
    float p2x = __fmul_rn(p1x, p1z);
    float p2y = __fmul_rn(p1y, p1z);
    float p2z = p1z;
    float ex = __fadd_rn(__fadd_rn(__fmul_rn(C[0],p2x), __fmul_rn(C[1],p2y)), __fmul_rn(C[2],p2z));
    float ey = __fadd_rn(__fadd_rn(__fmul_rn(C[3],p2x), __fmul_rn(C[4],p2y)), __fmul_rn(C[5],p2z));
    float ez = __fadd_rn(__fadd_rn(__fmul_rn(C[6],p2x), __fmul_rn(C[7],p2y)), __fmul_rn(C[8],p2z));
    float gx = __fadd_rn(ex, trx);
    float gy = __fadd_rn(ey, try_);
    float gz = __fadd_rn(ez, trz);

    float qx = __fdiv_rn(__fsub_rn(gx, -48.0f), 0.4f);
    float qy = __fdiv_rn(__fsub_rn(gy, -48.0f), 0.4f);
    float qz = __fdiv_rn(__fsub_rn(gz, -10.0f), 20.0f);
    int vx = (int)qx;   // trunc toward zero == astype(int32)
    int vy = (int)qy;
    int vz = (int)qz;

    bool kept = (vx >= 0) & (vx < NXX) & (vy >= 0) & (vy < NYY) & (vz == 0);
    unsigned long long bal = __ballot(kept);
    unsigned int mask = (unsigned int)((bal >> (sub*16)) & 0xFFFFull);

    if (h == 0) {
        int b_ = bn / NNC;
        int vb = b_*(NYY*NXX) + vy*NXX + vx;
        unsigned long long r = mask ? (((unsigned long long)mask << 32)
                                      | (unsigned int)vb)
                                    : 0ull;
        rec[tri] = r;                            // plain store, no atomic
    }
}

// v8 assemble_scan: 128 consecutive cells (half a y-row) per block, 1800
// blocks. Each block scans the dense 231 KB record array (L2/L3-resident;
// 4-deep unrolled loads for MLP). Matches are processed by the finding wave:
// v4's identical gather + shfl-xor reduce (same within-triple rounding),
// then ds_add_f32 accumulation into acc[128][65] (fire-and-forget LDS
// atomics — no global-atomic round trips anywhere). One barrier, then
// transpose-out with a 512 B contiguous run per c-plane.
__global__ void __launch_bounds__(256) assemble_scan(
        const float* __restrict__ x,
        const unsigned long long* __restrict__ rec,
        float* __restrict__ out) {
    __shared__ float acc[CELLS*65];              // 33.3 KB
    int tid  = threadIdx.x;
    int lane = tid & 63;
    int v0   = blockIdx.x * CELLS;

    for (int i = tid; i < CELLS*65; i += 256) acc[i] = 0.0f;
    __syncthreads();

    int hq = lane >> 4, c4 = lane & 15;

    // ---- scan all NTRI records, 4-deep load batches ----
    for (int k0 = 0; k0 < 113; k0 += 4) {
        unsigned long long r[4];
        #pragma unroll
        for (int u2 = 0; u2 < 4; ++u2) {
            int idx = (k0 + u2)*256 + tid;
            r[u2] = (idx < NTRI) ? rec[idx] : 0ull;
        }
        #pragma unroll
        for (int u2 = 0; u2 < 4; ++u2) {
            unsigned int vb = (unsigned int)r[u2];
            unsigned int m_ = (unsigned int)(r[u2] >> 32);
            bool match = (m_ != 0u) && ((unsigned int)(vb - (unsigned int)v0) < (unsigned int)CELLS);
            unsigned long long mm = __ballot(match);
            while (mm) {
                int j = __ffsll(mm) - 1;
                mm &= mm - 1;
                unsigned int vbj = (unsigned int)__shfl((int)vb, j);
                unsigned int mj  = (unsigned int)__shfl((int)m_, j);
                int trij = (k0 + u2)*256 + (tid & ~63) + j;   // wave-uniform

                int w    = trij % FWW;
                int rest = trij / FWW;
                int d    = rest % DDEP;
                int bn   = rest / DDEP;
                const float* xb = x + (size_t)((bn*DDEP + d)*FHH*FWW + w)*CC + c4*4;

                f4 a = (f4)(0.0f);
                #pragma unroll
                for (int rr = 0; rr < 4; ++rr) {
                    int hh = rr*4 + hq;
                    if ((mj >> hh) & 1u) {
                        f4 t = *(const f4*)(xb + (size_t)hh*(FWW*CC));
                        a += t;
                    }
                }
                // same reduce order as v4 -> identical within-triple rounding
                a.x += __shfl_xor(a.x, 16); a.y += __shfl_xor(a.y, 16);
                a.z += __shfl_xor(a.z, 16); a.w += __shfl_xor(a.w, 16);
                a.x += __shfl_xor(a.x, 32); a.y += __shfl_xor(a.y, 32);
                a.z += __shfl_xor(a.z, 32); a.w += __shfl_xor(a.w, 32);

                if (lane < 16) {
                    float* ap = &acc[(vbj - (unsigned int)v0)*65 + c4*4];
                    atomicAdd(ap + 0, a.x);      // ds_add_f32: no round trip
                    atomicAdd(ap + 1, a.y);
                    atomicAdd(ap + 2, a.z);
                    atomicAdd(ap + 3, a.w);
                }
            }
        }
    }
    __syncthreads();

    // ---- transpose out: one contiguous 512 B run per c-plane ----
    int b   = v0 / (NYY*NXX);
    int yx0 = v0 - b*(NYY*NXX);
    float* outb = out + (size_t)b*(CC*NYY*NXX) + yx0;
    #pragma unroll
    for (int it = 0; it < 8; ++it) {
        int s  = it*256 + tid;                   // 0..2047 = c*32 + xi
        int c  = s >> 5;
        int xi = s & 31;
        f4 f;
        f.x = acc[(xi*4 + 0)*65 + c];
        f.y = acc[(xi*4 + 1)*65 + c];
        f.z = acc[(xi*4 + 2)*65 + c];
        f.w = acc[(xi*4 + 3)*65 + c];
        __builtin_nontemporal_store(f, (f4*)(outb + (size_t)c*(NYY*NXX) + xi*4));
    }
}

extern "C" void kernel_launch(void* const* d_in, const int* in_sizes, int n_in,
                              void* d_out, int out_size, void* d_ws, size_t ws_size,
                              hipStream_t stream) {
    const float* x          = (const float*)d_in[0];
    const float* rots       = (const float*)d_in[1];
    const float* trans      = (const float*)d_in[2];
    const float* intrins    = (const float*)d_in[3];
    const float* post_rots  = (const float*)d_in[4];
    const float* post_trans = (const float*)d_in[5];
    float* out = (float*)d_out;

    unsigned long long* rec = (unsigned long long*)((char*)d_ws + W_REC);

    geom_rec<<<NTRI/16, 256, 0, stream>>>(rots, trans, intrins, post_rots,
                                          post_trans, rec);
    assemble_scan<<<NBLK, 256, 0, stream>>>(x, rec, out);
}

// Round 9
// 243.409 us; speedup vs baseline: 1.3548x; 1.3548x over previous
//
#include <hip/hip_runtime.h>

// ---- static problem config (mirrors reference init) ----
#define BB   4
#define NNC  4          // cameras
#define DDEP 41
#define FHH  16
#define FWW  44
#define CC   64
#define NXX  240
#define NYY  240
#define NVOX (BB*NYY*NXX)            // 230400 BEV cells (vz==0 plane)
#define NTRI (BB*NNC*DDEP*FWW)       // 28864 (b,n,d,u) column triples
#define SLOTS 8                      // max triples per cell (geometric bound ~4)

// ---- workspace layout (bytes) ----
#define W_CNT 0                          // uint cntp[NVOX/4] byte-packed      230400
#define W_MSK (NVOX)                     // uint tmask[NTRI]                   115456
#define W_TAB (W_MSK + NTRI*4)           // uint table[NVOX][SLOTS]           7372800
#define W_SCR (W_TAB + NVOX*SLOTS*4)     // f32  scratch[NTRI][CC]            7389184
// total ~= 15.1 MB

typedef float f4 __attribute__((ext_vector_type(4)));

// Replicate LAPACK sgetrf+strti2 on an UPPER-TRIANGULAR 3x3 in fp32, op-for-op.
__device__ __forceinline__ void inv3x3_upper_f32(const float K[9], float o[9]) {
    float a00 = __fdiv_rn(1.0f, K[0]);
    float a11 = __fdiv_rn(1.0f, K[4]);
    float a22 = __fdiv_rn(1.0f, K[8]);
    float b01 = __fmul_rn(-a11, __fmul_rn(a00, K[1]));
    float x0 = __fadd_rn(__fmul_rn(a00, K[2]), __fmul_rn(b01, K[5]));
    float x1 = __fmul_rn(a11, K[5]);
    float b02 = __fmul_rn(-a22, x0);
    float b12 = __fmul_rn(-a22, x1);
    o[0]=a00; o[1]=b01; o[2]=b02;
    o[3]=0.0f; o[4]=a11; o[5]=b12;
    o[6]=0.0f; o[7]=0.0f; o[8]=a22;
}

// v10 geom: identical to v9 (R0's byte-packed cnt + slot table + dense tmask
// store; no single-address atomics). Geometry chain bit-exact, UNCHANGED.
__global__ void __launch_bounds__(256) geom(
        const float* __restrict__ rots,
        const float* __restrict__ trans,
        const float* __restrict__ intrins,
        const float* __restrict__ post_rots,
        const float* __restrict__ post_trans,
        unsigned int* __restrict__ cntp,
        unsigned int* __restrict__ table,
        unsigned int* __restrict__ tmask) {
    int wid  = threadIdx.x >> 6;
    int lane = threadIdx.x & 63;
    int sub  = lane >> 4;
    int h    = lane & 15;
    int tri  = (blockIdx.x*4 + wid)*4 + sub;     // NTRI = 16*1804 exactly

    int w    = tri % FWW;
    int rest = tri / FWW;
    int d    = rest % DDEP;
    int bn   = rest / DDEP;

    float K[9], PR[9], R[9];
    #pragma unroll
    for (int i = 0; i < 9; ++i) {
        K[i]  = intrins[bn*9 + i];
        PR[i] = post_rots[bn*9 + i];
        R[i]  = rots[bn*9 + i];
    }
    float Ki[9], PRi[9];
    inv3x3_upper_f32(K, Ki);
    inv3x3_upper_f32(PR, PRi);
    float C[9];
    #pragma unroll
    for (int i = 0; i < 3; ++i)
        #pragma unroll
        for (int j = 0; j < 3; ++j) {
            float s = __fmul_rn(R[i*3+0], Ki[0*3+j]);
            s = __fadd_rn(s, __fmul_rn(R[i*3+1], Ki[1*3+j]));
            s = __fadd_rn(s, __fmul_rn(R[i*3+2], Ki[2*3+j]));
            C[i*3+j] = s;
        }
    float ptx = post_trans[bn*3+0], pty = post_trans[bn*3+1], ptz = post_trans[bn*3+2];
    float trx = trans[bn*3+0], try_ = trans[bn*3+1], trz = trans[bn*3+2];

    float u  = (float)((double)w * (703.0/43.0));   // np.linspace: f64 then f32 cast
    float v  = (float)((double)h * 17.0);
    float dd = (float)(4 + d);

    float p0x = __fsub_rn(u,  ptx);
    float p0y = __fsub_rn(v,  pty);
    float p0z = __fsub_rn(dd, ptz);
    float p1x = __fadd_rn(__fadd_rn(__fmul_rn(PRi[0],p0x), __fmul_rn(PRi[1],p0y)), __fmul_rn(PRi[2],p0z));
    float p1y = __fadd_rn(__fadd_rn(__fmul_rn(PRi[3],p0x), __fmul_rn(PRi[4],p0y)), __fmul_rn(PRi[5],p0z));
    float p1z = __fadd_rn(__fadd_rn(__fmul_rn(PRi[6],p0x), __fmul_rn(PRi[7],p0y)), __fmul_rn(PRi[8],p0z));
    float p2x = __fmul_rn(p1x, p1z);
    float p2y = __fmul_rn(p1y, p1z);
    float p2z = p1z;
    float ex = __fadd_rn(__fadd_rn(__fmul_rn(C[0],p2x), __fmul_rn(C[1],p2y)), __fmul_rn(C[2],p2z));
    float ey = __fadd_rn(__fadd_rn(__fmul_rn(C[3],p2x), __fmul_rn(C[4],p2y)), __fmul_rn(C[5],p2z));
    float ez = __fadd_rn(__fadd_rn(__fmul_rn(C[6],p2x), __fmul_rn(C[7],p2y)), __fmul_rn(C[8],p2z));
    float gx = __fadd_rn(ex, trx);
    float gy = __fadd_rn(ey, try_);
    float gz = __fadd_rn(ez, trz);

    float qx = __fdiv_rn(__fsub_rn(gx, -48.0f), 0.4f);
    float qy = __fdiv_rn(__fsub_rn(gy, -48.0f), 0.4f);
    float qz = __fdiv_rn(__fsub_rn(gz, -10.0f), 20.0f);
    int vx = (int)qx;   // trunc toward zero == astype(int32)
    int vy = (int)qy;
    int vz = (int)qz;

    bool kept = (vx >= 0) & (vx < NXX) & (vy >= 0) & (vy < NYY) & (vz == 0);
    unsigned long long bal = __ballot(kept);
    unsigned int mask = (unsigned int)((bal >> (sub*16)) & 0xFFFFull);

    if (h == 0) {
        tmask[tri] = mask;                       // dense, plain store
        if (mask != 0) {
            int b  = bn / NNC;
            int vb = b*(NYY*NXX) + vy*NXX + vx;
            unsigned int sh  = 8u*(vb & 3);
            unsigned int old = atomicAdd(&cntp[vb >> 2], 1u << sh);
            unsigned int sl  = (old >> sh) & 0xFFu;
            if (sl < SLOTS) table[vb*SLOTS + sl] = ((unsigned int)tri << 16) | mask;
        }
    }
}

// v10 colsum: identical to v9. One block per (b,n,d) slab; columnwise
// h-reduction with sequential coalesced reads; compact scratch[tri][64] out.
__global__ void __launch_bounds__(512) colsum(
        const float* __restrict__ x,
        const unsigned int* __restrict__ tmask,
        float* __restrict__ scratch) {
    __shared__ unsigned int smask[FWW];
    int tid  = threadIdx.x;
    int c    = tid & 63;                     // channel
    int wq   = tid >> 6;                     // 0..7, uniform per wave
    int blk  = blockIdx.x;                   // bn*DDEP + d  (656 slabs)
    int tribase = blk * FWW;

    if (tid < FWW) smask[tid] = tmask[tribase + tid];
    __syncthreads();

    const float* xs = x + (size_t)blk * (FHH*FWW*CC);

    float acc[6] = {0,0,0,0,0,0};
    for (int h = 0; h < FHH; ++h) {
        const float* row = xs + (size_t)h * (FWW*CC);
        #pragma unroll
        for (int j = 0; j < 6; ++j) {
            int w = j*8 + wq;                // wave-uniform
            if (w < FWW && ((smask[w] >> h) & 1u))
                acc[j] += row[w*CC + c];
        }
    }
    #pragma unroll
    for (int j = 0; j < 6; ++j) {
        int w = j*8 + wq;
        if (w < FWW)
            scratch[(size_t)(tribase + w)*CC + c] = acc[j];
    }
}

// v10 assemble2: v9 structure + THE FIX — __syncthreads() between the LDS
// zero-init and the per-wave cell writes. R8's failure (absmax 6.84 ~ one
// full cell sum) was this race: a fast wave stored its cell sum while a
// slow wave's zero-init stripe hadn't covered that address, and the late
// zero overwrote the sum. (v4 had the same latent race, hidden by its
// much longer gather loop.) dmask is block-uniform so all threads reach
// both barriers.
__global__ void __launch_bounds__(256) assemble2(
        const float* __restrict__ scratch,
        const unsigned int* __restrict__ cntp,
        const unsigned int* __restrict__ table,
        float* __restrict__ out) {
    __shared__ float lds[64*65];             // 16.6 KB: lds[cell*65 + channel]
    int tid  = threadIdx.x;
    int lane = tid & 63;
    int wid  = tid >> 6;
    int v0   = blockIdx.x * 64;              // 57600%64==0 -> no b-cross
    int b    = v0 / (NYY*NXX);
    int yx0  = v0 - b*(NYY*NXX);
    float* outb = out + (size_t)b*(CC*NYY*NXX) + yx0;

    // every wave loads the same 16 count words -> identical 64-bit dirty mask
    unsigned int cword = cntp[(v0 >> 2) + (lane >> 2)];
    unsigned int cbyte = (cword >> (8*(lane & 3))) & 0xFFu;
    unsigned long long dmask = __ballot(cbyte != 0u);    // block-uniform

    int sub = lane >> 4, xi = lane & 15;     // write mapping: 16 lanes = 256 B run

    if (dmask == 0ull) {
        f4 z = (f4)(0.0f);
        #pragma unroll
        for (int it = 0; it < 4; ++it) {
            int c = wid*16 + it*4 + sub;
            __builtin_nontemporal_store(z, (f4*)(outb + (size_t)c*(NYY*NXX) + xi*4));
        }
        return;
    }

    // ---- dirty block ----
    for (int i = tid; i < 64*65; i += 256) lds[i] = 0.0f;
    __syncthreads();                         // THE FIX: zero-init must complete
                                             // before any wave stores its sum

    unsigned long long m2 = dmask;
    int gi = 0;
    while (m2) {
        int cell = __ffsll((unsigned long long)m2) - 1;
        m2 &= m2 - 1;
        if ((gi++ & 3) != wid) continue;     // one cell per wave, round-robin

        int n = __shfl((int)cbyte, cell);
        if (n > SLOTS) n = SLOTS;
        unsigned int ent = (lane < n) ? table[(size_t)(v0 + cell)*SLOTS + lane] : 0u;

        float sum = 0.0f;                    // lane == channel
        for (int i = 0; i < n; ++i) {
            unsigned int e = (unsigned int)__shfl((int)ent, i);
            int tri = (int)(e >> 16);
            sum += scratch[(size_t)tri*CC + lane];   // coalesced 256 B, L2-hot
        }
        lds[cell*65 + lane] = sum;           // 2-way bank alias: free
    }
    __syncthreads();

    // transpose out: per plane c one contiguous 256 B run (64 cells x 4 B)
    #pragma unroll
    for (int it = 0; it < 4; ++it) {
        int c = wid*16 + it*4 + sub;
        f4 f;
        f.x = lds[(xi*4 + 0)*65 + c];
        f.y = lds[(xi*4 + 1)*65 + c];
        f.z = lds[(xi*4 + 2)*65 + c];
        f.w = lds[(xi*4 + 3)*65 + c];
        __builtin_nontemporal_store(f, (f4*)(outb + (size_t)c*(NYY*NXX) + xi*4));
    }
}

extern "C" void kernel_launch(void* const* d_in, const int* in_sizes, int n_in,
                              void* d_out, int out_size, void* d_ws, size_t ws_size,
                              hipStream_t stream) {
    const float* x          = (const float*)d_in[0];
    const float* rots       = (const float*)d_in[1];
    const float* trans      = (const float*)d_in[2];
    const float* intrins    = (const float*)d_in[3];
    const float* post_rots  = (const float*)d_in[4];
    const float* post_trans = (const float*)d_in[5];
    float* out = (float*)d_out;

    char* ws = (char*)d_ws;
    unsigned int* cntp    = (unsigned int*)(ws + W_CNT);
    unsigned int* tmask   = (unsigned int*)(ws + W_MSK);
    unsigned int* table   = (unsigned int*)(ws + W_TAB);
    float*        scratch = (float*)(ws + W_SCR);

    hipMemsetAsync(cntp, 0, NVOX, stream);                 // 230 KB
    geom<<<NTRI/16, 256, 0, stream>>>(rots, trans, intrins, post_rots, post_trans,
                                      cntp, table, tmask);
    colsum<<<BB*NNC*DDEP, 512, 0, stream>>>(x, tmask, scratch);
    assemble2<<<NVOX/64, 256, 0, stream>>>(scratch, cntp, table, out);
}